// Round 2
// baseline (62776.819 us; speedup 1.0000x reference)
//
#include <hip/hip_runtime.h>
#include <hip/hip_bf16.h>

static constexpr int T_  = 512;
static constexpr int B_  = 64;
static constexpr int I_  = 128;
static constexpr int H_  = 2048;
static constexpr int H1_ = 1024;
static constexpr int F2_ = 512;
static constexpr int H2_ = 256;
static constexpr int O_  = 64;
static constexpr int G1N = 4096;
static constexpr int G2N = 1024;

typedef __attribute__((ext_vector_type(8))) __bf16 bfx8;
typedef __attribute__((ext_vector_type(4))) __bf16 bfx4;
typedef __attribute__((ext_vector_type(4))) float  fx4;

#define DEV __device__ __forceinline__

DEV fx4 mfma16(bfx8 a, bfx8 b, fx4 c) {
  return __builtin_amdgcn_mfma_f32_16x16x32_bf16(a, b, c, 0, 0, 0);
}
DEV float fast_sig(float x) { return 1.0f / (1.0f + __expf(-x)); }
DEV float fast_tanh(float x) {
  x = fminf(fmaxf(x, -30.0f), 30.0f);
  return 2.0f / (1.0f + __expf(-2.0f * x)) - 1.0f;
}
DEV float leaky_tanh_(float x) { return fast_tanh(x * (2.0f / 3.0f)) * 1.7159f + 0.01f * x; }

// ---- cross-block sync (monotonic counters, agent scope) ----
DEV void waitge(int* p, int tgt) {
  if (threadIdx.x == 0) {
    while (__hip_atomic_load(p, __ATOMIC_ACQUIRE, __HIP_MEMORY_SCOPE_AGENT) < tgt)
      __builtin_amdgcn_s_sleep(1);
  }
  __syncthreads();
}
DEV void arrive(int* p) {
  __syncthreads();  // drains all threads' stores (vmcnt0 at barrier) before release
  if (threadIdx.x == 0)
    __hip_atomic_fetch_add(p, 1, __ATOMIC_RELEASE, __HIP_MEMORY_SCOPE_AGENT);
}

// ---- fp32 -> bf16 ----
__global__ void k_f2b(const float* __restrict__ s, __bf16* __restrict__ d, int n4) {
  int i = blockIdx.x * blockDim.x + threadIdx.x;
  int st = gridDim.x * blockDim.x;
  for (; i < n4; i += st) {
    float4 v = ((const float4*)s)[i];
    bfx4 o = { (__bf16)v.x, (__bf16)v.y, (__bf16)v.z, (__bf16)v.w };
    ((bfx4*)d)[i] = o;
  }
}
__global__ void k_add2(const float* __restrict__ a, const float* __restrict__ b,
                       float* __restrict__ d, int n) {
  int i = blockIdx.x * blockDim.x + threadIdx.x;
  if (i < n) d[i] = a[i] + b[i];
}

// ---- big GEMM: C[M,N] = A[M,K](bf16) @ W[N,K](bf16)^T ----
// epi 1: bf16 leaky_tanh(v+bias) -> outB ; epi 2: fp32 v+bias -> outF
__launch_bounds__(256)
__global__ void k_gemm(const __bf16* __restrict__ A, const __bf16* __restrict__ W,
                       float* __restrict__ outF, __bf16* __restrict__ outB,
                       const float* __restrict__ bias,
                       int M, int N, int K, int epi)
{
  __shared__ __bf16 As[128][32];
  __shared__ __bf16 Ws[128][32];
  const int tid = threadIdx.x;
  const int lane = tid & 63;
  const int wave = tid >> 6;
  const int wm = wave >> 1, wn = wave & 1;
  const int m0 = blockIdx.y * 128, n0 = blockIdx.x * 128;
  const int r1 = tid >> 2, c1v = (tid & 3) * 8;
  const int kr = (lane >> 4) * 8, rr = lane & 15;
  fx4 acc[4][4] = {};
  for (int k0 = 0; k0 < K; k0 += 32) {
    __syncthreads();
    *(bfx8*)&As[r1][c1v]      = *(const bfx8*)&A[(size_t)(m0 + r1) * K + k0 + c1v];
    *(bfx8*)&As[r1 + 64][c1v] = *(const bfx8*)&A[(size_t)(m0 + r1 + 64) * K + k0 + c1v];
    *(bfx8*)&Ws[r1][c1v]      = *(const bfx8*)&W[(size_t)(n0 + r1) * K + k0 + c1v];
    *(bfx8*)&Ws[r1 + 64][c1v] = *(const bfx8*)&W[(size_t)(n0 + r1 + 64) * K + k0 + c1v];
    __syncthreads();
    bfx8 a[4], b[4];
#pragma unroll
    for (int mi = 0; mi < 4; ++mi) a[mi] = *(const bfx8*)&As[wm*64 + mi*16 + rr][kr];
#pragma unroll
    for (int ni = 0; ni < 4; ++ni) b[ni] = *(const bfx8*)&Ws[wn*64 + ni*16 + rr][kr];
#pragma unroll
    for (int mi = 0; mi < 4; ++mi)
#pragma unroll
      for (int ni = 0; ni < 4; ++ni)
        acc[mi][ni] = mfma16(a[mi], b[ni], acc[mi][ni]);
  }
  const int cr = (lane >> 4) * 4, cc = lane & 15;
#pragma unroll
  for (int mi = 0; mi < 4; ++mi)
#pragma unroll
    for (int ni = 0; ni < 4; ++ni) {
      int col = n0 + wn*64 + ni*16 + cc;
#pragma unroll
      for (int r = 0; r < 4; ++r) {
        int row = m0 + wm*64 + mi*16 + cr + r;
        float v = acc[mi][ni][r];
        if (epi == 1) outB[(size_t)row * N + col] = (__bf16)leaky_tanh_(v + bias[col]);
        else          outF[(size_t)row * N + col] = v + bias[col];
      }
    }
}

// ---- LDS stage helper: global bf16 [rows][srcStride] -> LDS rows of rsB bytes,
//      16B chunks XOR-swizzled by ((row&7)<<4). n = rows * (cols/8), lg = log2(cols/8).
DEV void stage(char* dst, int rsB, const __bf16* __restrict__ src, size_t sStride,
               int n, int lg) {
  for (int idx = threadIdx.x; idx < n; idx += 256) {
    int r = idx >> lg, c = idx & ((1 << lg) - 1);
    *(bfx8*)(dst + r * rsB + ((c * 16) ^ ((r & 7) << 4))) =
        *(const bfx8*)(src + (size_t)r * sStride + c * 8);
  }
}

// ---- persistent recurrent kernel ----
// grid 241: [0,128) LSTM1 (ng=bid>>2 of 32 hidden cols, kg=bid&3 K-slice 256)
//           [128,192) fc2 (ng 32 x 16 cols, kg 2 K-half 512)
//           [192,224) LSTM2 (ng 32 x 8 hidden cols)
//           [224,240) hh2 partial (ng 16 x 16 hidden cols)
//           [240] fc3
// counters: 0 h1(+32/t) 1 p1(+96/t) 2 p2(+32/t) 3 x2(+32/t) 4 g2p(+16/t) 5 h2(+32/t) 6 y(+1/t)
__launch_bounds__(256)
__global__ void k_persist(
    const __bf16* __restrict__ whh1b, const __bf16* __restrict__ wfc2b,
    const __bf16* __restrict__ wih2b, const __bf16* __restrict__ whh2b,
    const __bf16* __restrict__ wfc3b,
    const float* __restrict__ G1c, const float* __restrict__ bfc2,
    const float* __restrict__ bsum2, const float* __restrict__ b3,
    __bf16* __restrict__ h1, float* __restrict__ c1,
    __bf16* __restrict__ h2, float* __restrict__ c2,
    __bf16* __restrict__ x2, float* __restrict__ g2p,
    float* __restrict__ p1, float* __restrict__ p2,
    float* __restrict__ out, int* __restrict__ cnt,
    int t0, int Tc)
{
  __shared__ __align__(16) char smem[98304];
  const int tid = threadIdx.x, lane = tid & 63, wv = tid >> 6;
  const int rr = lane & 15, hi = lane >> 4;
  const int cc = lane & 15;
  const int bid = blockIdx.x;

  if (bid < 128) {
    // ================= LSTM1 =================
    const int ng = bid >> 2, kg = bid & 3;
    char* Ws = smem;            // 128 rows x 512B (64KB)
    char* As = smem + 65536;    // 64 rows x 512B (32KB); Gx alias [128][64] f32
    for (int idx = tid; idx < 4096; idx += 256) {
      int r = idx >> 5, c = idx & 31;
      int g = r >> 5, j = r & 31;
      const __bf16* sp = whh1b + (size_t)(g * 1024 + ng * 32 + j) * 1024 + kg * 256 + c * 8;
      *(bfx8*)(Ws + r * 512 + ((c * 16) ^ ((r & 7) << 4))) = *(const bfx8*)sp;
    }
    __syncthreads();
    for (int s = 0; s < Tc; ++s) {
      const int t = t0 + s;
      waitge(cnt + 0, 32 * t);
      if (kg == 0 && t >= 2) { waitge(cnt + 2, 32 * (t - 1)); waitge(cnt + 3, 32 * (t - 1)); }
      stage(As, 512, h1 + (size_t)(t & 1) * 65536 + kg * 256, 1024, 2048, 5);
      __syncthreads();
      fx4 acc[4][2] = {};
#pragma unroll
      for (int kk = 0; kk < 8; ++kk) {
        const int cb = kk * 64 + hi * 16;
        bfx8 a[4], b[2];
#pragma unroll
        for (int m = 0; m < 4; ++m) {
          int r = m * 16 + rr;
          a[m] = *(const bfx8*)(As + r * 512 + (cb ^ ((r & 7) << 4)));
        }
#pragma unroll
        for (int n = 0; n < 2; ++n) {
          int r = wv * 32 + n * 16 + rr;
          b[n] = *(const bfx8*)(Ws + r * 512 + (cb ^ ((r & 7) << 4)));
        }
#pragma unroll
        for (int m = 0; m < 4; ++m)
#pragma unroll
          for (int n = 0; n < 2; ++n)
            acc[m][n] = mfma16(a[m], b[n], acc[m][n]);
      }
      __syncthreads();
      if (kg) {
        float* pp = p1 + ((size_t)(kg - 1) * 32 + ng) * 8192;  // [b][128 rows]
#pragma unroll
        for (int m = 0; m < 4; ++m)
#pragma unroll
          for (int n = 0; n < 2; ++n)
#pragma unroll
            for (int r = 0; r < 4; ++r)
              pp[(m * 16 + hi * 4 + r) * 128 + wv * 32 + n * 16 + cc] = acc[m][n][r];
        arrive(cnt + 1);
      } else {
        // own partial -> Gx (aliases As), swizzled fp32 [row][b]
#pragma unroll
        for (int m = 0; m < 4; ++m)
#pragma unroll
          for (int n = 0; n < 2; ++n)
#pragma unroll
            for (int r = 0; r < 4; ++r) {
              int row = wv * 32 + n * 16 + cc, b_ = m * 16 + hi * 4 + r;
              *(float*)(As + row * 256 + ((b_ * 4) ^ ((row & 7) << 2))) = acc[m][n][r];
            }
        __syncthreads();
        waitge(cnt + 1, 96 * (t + 1));
        const int hc = tid & 31, bb = tid >> 5;
#pragma unroll
        for (int q = 0; q < 8; ++q) {
          int b_ = bb * 8 + q;
          float gv[4];
#pragma unroll
          for (int g = 0; g < 4; ++g) {
            int row = g * 32 + hc;
            float v = *(const float*)(As + row * 256 + ((b_ * 4) ^ ((row & 7) << 2)));
            v += p1[((size_t)0 * 32 + ng) * 8192 + b_ * 128 + row];
            v += p1[((size_t)1 * 32 + ng) * 8192 + b_ * 128 + row];
            v += p1[((size_t)2 * 32 + ng) * 8192 + b_ * 128 + row];
            v += G1c[(size_t)(s * 64 + b_) * 4096 + g * 1024 + ng * 32 + hc];
            gv[g] = v;
          }
          int ci = b_ * 1024 + ng * 32 + hc;
          float cp = c1[ci];
          float cn = fast_sig(gv[1]) * cp + fast_sig(gv[0]) * fast_tanh(gv[2]);
          c1[ci] = cn;
          h1[(size_t)((t + 1) & 1) * 65536 + ci] = (__bf16)(fast_sig(gv[3]) * fast_tanh(cn));
        }
        arrive(cnt + 0);
      }
    }
  } else if (bid < 192) {
    // ================= fc2 =================
    const int ii = bid - 128, ng = ii >> 1, kg = ii & 1;
    char* Ws = smem;            // 16 x 1024B (16KB)
    char* As = smem + 16384;    // 64 x 1024B (64KB); Gx2 alias [16][64] f32 (4KB)
    for (int idx = tid; idx < 1024; idx += 256) {
      int r = idx >> 6, c = idx & 63;
      const __bf16* sp = wfc2b + (size_t)(ng * 16 + r) * 1024 + kg * 512 + c * 8;
      *(bfx8*)(Ws + r * 1024 + ((c * 16) ^ ((r & 7) << 4))) = *(const bfx8*)sp;
    }
    __syncthreads();
    for (int s = 0; s < Tc; ++s) {
      const int t = t0 + s;
      waitge(cnt + 0, 32 * (t + 1));
      if (t >= 2) waitge(cnt + 5, 32 * (t - 1));
      if (kg && t >= 1) waitge(cnt + 3, 32 * t);
      stage(As, 1024, h1 + (size_t)((t + 1) & 1) * 65536 + kg * 512, 1024, 4096, 6);
      __syncthreads();
      fx4 acc = {};
#pragma unroll
      for (int kk = 0; kk < 16; ++kk) {
        const int cb = kk * 64 + hi * 16;
        int ra = wv * 16 + rr;
        bfx8 a = *(const bfx8*)(As + ra * 1024 + (cb ^ ((ra & 7) << 4)));
        bfx8 b = *(const bfx8*)(Ws + rr * 1024 + (cb ^ ((rr & 7) << 4)));
        acc = mfma16(a, b, acc);
      }
      __syncthreads();
      if (kg) {
        float* pp = p2 + (size_t)ng * 1024;  // [b][16]
#pragma unroll
        for (int r = 0; r < 4; ++r)
          pp[(wv * 16 + hi * 4 + r) * 16 + cc] = acc[r];
        arrive(cnt + 2);
      } else {
#pragma unroll
        for (int r = 0; r < 4; ++r) {
          int b_ = wv * 16 + hi * 4 + r;
          *(float*)(As + cc * 256 + ((b_ * 4) ^ ((cc & 7) << 2))) = acc[r];
        }
        __syncthreads();
        waitge(cnt + 2, 32 * (t + 1));
        const int col = tid & 15, b4 = tid >> 4;
#pragma unroll
        for (int q = 0; q < 4; ++q) {
          int b_ = b4 * 4 + q;
          float v = *(const float*)(As + col * 256 + ((b_ * 4) ^ ((col & 7) << 2)));
          v += p2[(size_t)ng * 1024 + b_ * 16 + col] + bfc2[ng * 16 + col];
          x2[(size_t)(t & 1) * 32768 + b_ * 512 + ng * 16 + col] = (__bf16)leaky_tanh_(v);
        }
        arrive(cnt + 3);
      }
    }
  } else if (bid < 224) {
    // ================= LSTM2 =================
    const int ng = bid - 192;   // 8 hidden cols
    char* Ws = smem;            // 32 x 1024B (32KB)
    char* As = smem + 32768;    // 64 x 1024B (64KB); Gx3 alias [32][64] f32 (8KB)
    for (int idx = tid; idx < 2048; idx += 256) {
      int r = idx >> 6, c = idx & 63;
      int g = r >> 3, j = r & 7;
      const __bf16* sp = wih2b + (size_t)(g * 256 + ng * 8 + j) * 512 + c * 8;
      *(bfx8*)(Ws + r * 1024 + ((c * 16) ^ ((r & 7) << 4))) = *(const bfx8*)sp;
    }
    __syncthreads();
    for (int s = 0; s < Tc; ++s) {
      const int t = t0 + s;
      waitge(cnt + 3, 32 * (t + 1));
      waitge(cnt + 4, 16 * (t + 1));
      if (t >= 2) waitge(cnt + 6, t - 1);
      stage(As, 1024, x2 + (size_t)(t & 1) * 32768, 512, 4096, 6);
      __syncthreads();
      fx4 acc[2] = {};
#pragma unroll
      for (int kk = 0; kk < 16; ++kk) {
        const int cb = kk * 64 + hi * 16;
        int ra = wv * 16 + rr;
        bfx8 a = *(const bfx8*)(As + ra * 1024 + (cb ^ ((ra & 7) << 4)));
#pragma unroll
        for (int n = 0; n < 2; ++n) {
          int rb = n * 16 + rr;
          bfx8 b = *(const bfx8*)(Ws + rb * 1024 + (cb ^ ((rb & 7) << 4)));
          acc[n] = mfma16(a, b, acc[n]);
        }
      }
      __syncthreads();
#pragma unroll
      for (int n = 0; n < 2; ++n)
#pragma unroll
        for (int r = 0; r < 4; ++r) {
          int row = n * 16 + cc, b_ = wv * 16 + hi * 4 + r;
          *(float*)(As + row * 256 + ((b_ * 4) ^ ((row & 7) << 2))) = acc[n][r];
        }
      __syncthreads();
      const int hc = tid & 7, b0 = tid >> 3;
#pragma unroll
      for (int q = 0; q < 2; ++q) {
        int b_ = b0 + q * 32;
        float gv[4];
#pragma unroll
        for (int g = 0; g < 4; ++g) {
          int row = g * 8 + hc;
          gv[g] = *(const float*)(As + row * 256 + ((b_ * 4) ^ ((row & 7) << 2)))
                + g2p[(size_t)(t & 1) * 65536 + b_ * 1024 + g * 256 + ng * 8 + hc];
        }
        int ci = b_ * 256 + ng * 8 + hc;
        float cp = c2[ci];
        float cn = fast_sig(gv[1]) * cp + fast_sig(gv[0]) * fast_tanh(gv[2]);
        c2[ci] = cn;
        h2[(size_t)((t + 1) & 1) * 16384 + ci] = (__bf16)(fast_sig(gv[3]) * fast_tanh(cn));
      }
      arrive(cnt + 5);
    }
  } else if (bid < 240) {
    // ================= hh2 partial (+biases) =================
    const int ng = bid - 224;   // 16 hidden cols
    char* Ws = smem;            // 64 x 512B (32KB)
    char* As = smem + 32768;    // 64 x 512B (32KB)
    for (int idx = tid; idx < 2048; idx += 256) {
      int r = idx >> 5, c = idx & 31;
      int g = r >> 4, j = r & 15;
      const __bf16* sp = whh2b + (size_t)(g * 256 + ng * 16 + j) * 256 + c * 8;
      *(bfx8*)(Ws + r * 512 + ((c * 16) ^ ((r & 7) << 4))) = *(const bfx8*)sp;
    }
    __syncthreads();
    for (int s = 0; s < Tc; ++s) {
      const int t = t0 + s;
      waitge(cnt + 5, 32 * t);
      stage(As, 512, h2 + (size_t)(t & 1) * 16384, 256, 2048, 5);
      __syncthreads();
      fx4 acc[4] = {};
#pragma unroll
      for (int kk = 0; kk < 8; ++kk) {
        const int cb = kk * 64 + hi * 16;
        int ra = wv * 16 + rr;
        bfx8 a = *(const bfx8*)(As + ra * 512 + (cb ^ ((ra & 7) << 4)));
#pragma unroll
        for (int n = 0; n < 4; ++n) {
          int rb = n * 16 + rr;
          bfx8 b = *(const bfx8*)(Ws + rb * 512 + (cb ^ ((rb & 7) << 4)));
          acc[n] = mfma16(a, b, acc[n]);
        }
      }
#pragma unroll
      for (int n = 0; n < 4; ++n)
#pragma unroll
        for (int r = 0; r < 4; ++r) {
          int lrow = n * 16 + cc;
          int g = lrow >> 4, j = lrow & 15;
          int grow = g * 256 + ng * 16 + j;
          int b_ = wv * 16 + hi * 4 + r;
          g2p[(size_t)(t & 1) * 65536 + b_ * 1024 + grow] = acc[n][r] + bsum2[grow];
        }
      arrive(cnt + 4);
    }
  } else {
    // ================= fc3 =================
    char* Ws = smem;            // 64 x 512B
    char* As = smem + 32768;    // 64 x 512B
    for (int idx = tid; idx < 2048; idx += 256) {
      int r = idx >> 5, c = idx & 31;
      const __bf16* sp = wfc3b + (size_t)r * 256 + c * 8;
      *(bfx8*)(Ws + r * 512 + ((c * 16) ^ ((r & 7) << 4))) = *(const bfx8*)sp;
    }
    __syncthreads();
    for (int s = 0; s < Tc; ++s) {
      const int t = t0 + s;
      waitge(cnt + 5, 32 * (t + 1));
      stage(As, 512, h2 + (size_t)((t + 1) & 1) * 16384, 256, 2048, 5);
      __syncthreads();
      fx4 acc[4] = {};
#pragma unroll
      for (int kk = 0; kk < 8; ++kk) {
        const int cb = kk * 64 + hi * 16;
        int ra = wv * 16 + rr;
        bfx8 a = *(const bfx8*)(As + ra * 512 + (cb ^ ((ra & 7) << 4)));
#pragma unroll
        for (int n = 0; n < 4; ++n) {
          int rb = n * 16 + rr;
          bfx8 b = *(const bfx8*)(Ws + rb * 512 + (cb ^ ((rb & 7) << 4)));
          acc[n] = mfma16(a, b, acc[n]);
        }
      }
#pragma unroll
      for (int n = 0; n < 4; ++n)
#pragma unroll
        for (int r = 0; r < 4; ++r) {
          int col = n * 16 + cc, b_ = wv * 16 + hi * 4 + r;
          out[(size_t)t * 4096 + b_ * 64 + col] = acc[n][r] + b3[col];
        }
      arrive(cnt + 6);
    }
  }
}

// ---------------- host launcher ----------------
extern "C" void kernel_launch(void* const* d_in, const int* in_sizes, int n_in,
                              void* d_out, int out_size, void* d_ws, size_t ws_size,
                              hipStream_t stream)
{
  (void)in_sizes; (void)n_in; (void)out_size;
  const float* f_in = (const float*)d_in[0];
  const float* fc1w = (const float*)d_in[1];
  const float* fc1b = (const float*)d_in[2];
  const float* wih1 = (const float*)d_in[3];
  const float* whh1 = (const float*)d_in[4];
  const float* bih1 = (const float*)d_in[5];
  const float* bhh1 = (const float*)d_in[6];
  const float* fc2w = (const float*)d_in[7];
  const float* fc2b = (const float*)d_in[8];
  const float* wih2 = (const float*)d_in[9];
  const float* whh2 = (const float*)d_in[10];
  const float* bih2 = (const float*)d_in[11];
  const float* bhh2 = (const float*)d_in[12];
  const float* fc3w = (const float*)d_in[13];
  const float* fc3b = (const float*)d_in[14];
  float* out = (float*)d_out;

  char* base = (char*)d_ws;
  size_t off = 0;
  auto alloc = [&](size_t bytes) -> char* {
    char* q = base + off;
    off = (off + bytes + 255) & ~(size_t)255;
    return q;
  };
  __bf16* wb_fc1 = (__bf16*)alloc((size_t)H_ * I_ * 2);
  __bf16* wb_ih1 = (__bf16*)alloc((size_t)G1N * H_ * 2);
  __bf16* wb_hh1 = (__bf16*)alloc((size_t)G1N * H1_ * 2);
  __bf16* wb_fc2 = (__bf16*)alloc((size_t)F2_ * H1_ * 2);
  __bf16* wb_ih2 = (__bf16*)alloc((size_t)G2N * F2_ * 2);
  __bf16* wb_hh2 = (__bf16*)alloc((size_t)G2N * H2_ * 2);
  __bf16* wb_fc3 = (__bf16*)alloc((size_t)O_ * H2_ * 2);
  __bf16* in_bf  = (__bf16*)alloc((size_t)T_ * B_ * I_ * 2);
  float*  bsum1  = (float*) alloc((size_t)G1N * 4);
  float*  bsum2  = (float*) alloc((size_t)G2N * 4);
  float*  p1     = (float*) alloc((size_t)96 * 8192 * 4);
  float*  p2     = (float*) alloc((size_t)32 * 1024 * 4);
  float*  g2p    = (float*) alloc((size_t)2 * B_ * G2N * 4);
  __bf16* x2     = (__bf16*)alloc((size_t)2 * B_ * F2_ * 2);
  // zero-init span: h1b .. cnt (contiguous below)
  __bf16* h1b    = (__bf16*)alloc((size_t)2 * B_ * H1_ * 2);
  float*  c1     = (float*) alloc((size_t)B_ * H1_ * 4);
  __bf16* h2b    = (__bf16*)alloc((size_t)2 * B_ * H2_ * 2);
  float*  c2     = (float*) alloc((size_t)B_ * H2_ * 4);
  int*    cnt    = (int*)   alloc(64);
  size_t zbytes = (size_t)((char*)cnt + 64 - (char*)h1b);

  size_t fixed = off;
  int Tc = 128;
  while (Tc > 2 && fixed + (size_t)Tc * 64 * ((size_t)H_ * 2 + (size_t)G1N * 4) + 8192 > ws_size)
    Tc >>= 1;
  __bf16* Xc  = (__bf16*)alloc((size_t)Tc * 64 * H_ * 2);
  float*  G1c = (float*) alloc((size_t)Tc * 64 * G1N * 4);

  struct CV { const float* s; __bf16* d; int n; } cvs[8] = {
    {fc1w, wb_fc1, H_ * I_},   {wih1, wb_ih1, G1N * H_},  {whh1, wb_hh1, G1N * H1_},
    {fc2w, wb_fc2, F2_ * H1_}, {wih2, wb_ih2, G2N * F2_}, {whh2, wb_hh2, G2N * H2_},
    {fc3w, wb_fc3, O_ * H2_},  {f_in, in_bf, T_ * B_ * I_},
  };
  for (int i = 0; i < 8; ++i) {
    int n4 = cvs[i].n / 4;
    int blocks = (n4 + 255) / 256;
    if (blocks > 2048) blocks = 2048;
    k_f2b<<<blocks, 256, 0, stream>>>(cvs[i].s, cvs[i].d, n4);
  }
  k_add2<<<G1N / 256, 256, 0, stream>>>(bih1, bhh1, bsum1, G1N);
  k_add2<<<G2N / 256, 256, 0, stream>>>(bih2, bhh2, bsum2, G2N);
  hipMemsetAsync(h1b, 0, zbytes, stream);

  const int Mc = Tc * 64;
  const int chunks = T_ / Tc;
  for (int ch = 0; ch < chunks; ++ch) {
    k_gemm<<<dim3(H_ / 128, Mc / 128), 256, 0, stream>>>(
        in_bf + (size_t)ch * Mc * I_, wb_fc1, nullptr, Xc, fc1b, Mc, H_, I_, 1);
    k_gemm<<<dim3(G1N / 128, Mc / 128), 256, 0, stream>>>(
        Xc, wb_ih1, G1c, nullptr, bsum1, Mc, G1N, H_, 2);
    k_persist<<<241, 256, 0, stream>>>(
        wb_hh1, wb_fc2, wb_ih2, wb_hh2, wb_fc3,
        G1c, fc2b, bsum2, fc3b,
        h1b, c1, h2b, c2, x2, g2p, p1, p2,
        out, cnt, ch * Tc, Tc);
  }
}

// Round 3
// 6314.745 us; speedup vs baseline: 9.9413x; 9.9413x over previous
//
#include <hip/hip_runtime.h>
#include <hip/hip_bf16.h>

static constexpr int T_  = 512;
static constexpr int B_  = 64;
static constexpr int I_  = 128;
static constexpr int H_  = 2048;
static constexpr int H1_ = 1024;
static constexpr int F2_ = 512;
static constexpr int H2_ = 256;
static constexpr int O_  = 64;
static constexpr int G1N = 4096;
static constexpr int G2N = 1024;

typedef __attribute__((ext_vector_type(8))) __bf16 bfx8;
typedef __attribute__((ext_vector_type(4))) __bf16 bfx4;
typedef __attribute__((ext_vector_type(4))) float  fx4;

#define DEV __device__ __forceinline__

DEV fx4 mfma16(bfx8 a, bfx8 b, fx4 c) {
  return __builtin_amdgcn_mfma_f32_16x16x32_bf16(a, b, c, 0, 0, 0);
}
DEV float fast_sig(float x) { return 1.0f / (1.0f + __expf(-x)); }
DEV float fast_tanh(float x) {
  x = fminf(fmaxf(x, -30.0f), 30.0f);
  return 2.0f / (1.0f + __expf(-2.0f * x)) - 1.0f;
}
DEV float leaky_tanh_(float x) { return fast_tanh(x * (2.0f / 3.0f)) * 1.7159f + 0.01f * x; }

// ---- fp32 -> bf16 ----
__global__ void k_f2b(const float* __restrict__ s, __bf16* __restrict__ d, int n4) {
  int i = blockIdx.x * blockDim.x + threadIdx.x;
  int st = gridDim.x * blockDim.x;
  for (; i < n4; i += st) {
    float4 v = ((const float4*)s)[i];
    bfx4 o = { (__bf16)v.x, (__bf16)v.y, (__bf16)v.z, (__bf16)v.w };
    ((bfx4*)d)[i] = o;
  }
}
__global__ void k_add2(const float* __restrict__ a, const float* __restrict__ b,
                       float* __restrict__ d, int n) {
  int i = blockIdx.x * blockDim.x + threadIdx.x;
  if (i < n) d[i] = a[i] + b[i];
}

// ---- big GEMM: C[M,N] = A[M,K](bf16) @ W[N,K](bf16)^T ----
// epi 1: bf16 leaky_tanh(v+bias) -> outB ; epi 2: fp32 v+bias -> outF
__launch_bounds__(256)
__global__ void k_gemm(const __bf16* __restrict__ A, const __bf16* __restrict__ W,
                       float* __restrict__ outF, __bf16* __restrict__ outB,
                       const float* __restrict__ bias,
                       int M, int N, int K, int epi)
{
  __shared__ __bf16 As[128][32];
  __shared__ __bf16 Ws[128][32];
  const int tid = threadIdx.x;
  const int lane = tid & 63;
  const int wave = tid >> 6;
  const int wm = wave >> 1, wn = wave & 1;
  const int m0 = blockIdx.y * 128, n0 = blockIdx.x * 128;
  const int r1 = tid >> 2, c1v = (tid & 3) * 8;
  const int kr = (lane >> 4) * 8, rr = lane & 15;
  fx4 acc[4][4] = {};
  for (int k0 = 0; k0 < K; k0 += 32) {
    __syncthreads();
    *(bfx8*)&As[r1][c1v]      = *(const bfx8*)&A[(size_t)(m0 + r1) * K + k0 + c1v];
    *(bfx8*)&As[r1 + 64][c1v] = *(const bfx8*)&A[(size_t)(m0 + r1 + 64) * K + k0 + c1v];
    *(bfx8*)&Ws[r1][c1v]      = *(const bfx8*)&W[(size_t)(n0 + r1) * K + k0 + c1v];
    *(bfx8*)&Ws[r1 + 64][c1v] = *(const bfx8*)&W[(size_t)(n0 + r1 + 64) * K + k0 + c1v];
    __syncthreads();
    bfx8 a[4], b[4];
#pragma unroll
    for (int mi = 0; mi < 4; ++mi) a[mi] = *(const bfx8*)&As[wm*64 + mi*16 + rr][kr];
#pragma unroll
    for (int ni = 0; ni < 4; ++ni) b[ni] = *(const bfx8*)&Ws[wn*64 + ni*16 + rr][kr];
#pragma unroll
    for (int mi = 0; mi < 4; ++mi)
#pragma unroll
      for (int ni = 0; ni < 4; ++ni)
        acc[mi][ni] = mfma16(a[mi], b[ni], acc[mi][ni]);
  }
  const int cr = (lane >> 4) * 4, cc = lane & 15;
#pragma unroll
  for (int mi = 0; mi < 4; ++mi)
#pragma unroll
    for (int ni = 0; ni < 4; ++ni) {
      int col = n0 + wn*64 + ni*16 + cc;
#pragma unroll
      for (int r = 0; r < 4; ++r) {
        int row = m0 + wm*64 + mi*16 + cr + r;
        float v = acc[mi][ni][r];
        if (epi == 1) outB[(size_t)row * N + col] = (__bf16)leaky_tanh_(v + bias[col]);
        else          outF[(size_t)row * N + col] = v + bias[col];
      }
    }
}

// ---- LDS stage helper (XOR-swizzled 16B chunks), proven in round 2 ----
DEV void stage(char* dst, int rsB, const __bf16* __restrict__ src, size_t sStride,
               int n, int lg) {
  for (int idx = threadIdx.x; idx < n; idx += 256) {
    int r = idx >> lg, c = idx & ((1 << lg) - 1);
    *(bfx8*)(dst + r * rsB + ((c * 16) ^ ((r & 7) << 4))) =
        *(const bfx8*)(src + (size_t)r * sStride + c * 8);
  }
}

// ---- per-step kernel: blocks [0,64) LSTM1(t); blocks [64,80) LSTM2(t-Tc) ----
// do_l1==0: grid 16, all blocks take the LSTM2 role.
__launch_bounds__(256)
__global__ void k_step(int do_l1, int do_l2, int s,
                       const __bf16* __restrict__ h1_in, __bf16* __restrict__ h1_out,
                       float* __restrict__ c1, const __bf16* __restrict__ whh1b,
                       const float* __restrict__ G1c,
                       const __bf16* __restrict__ h2_in, __bf16* __restrict__ h2_out,
                       float* __restrict__ c2, const __bf16* __restrict__ whh2b,
                       const float* __restrict__ G2c)
{
  __shared__ __align__(16) char smem[81920];
  const int tid = threadIdx.x, lane = tid & 63, wv = tid >> 6;
  const int rr = lane & 15, hi = lane >> 4;
  const int bid = blockIdx.x;
  const int ecol = tid & 15, ebrow = tid >> 4;   // epilogue (col, batch-row base)
  const int tc = tid & 15, tr = tid >> 4;        // tile load (chunk, row base)

  if (do_l1 && bid < 64) {
    // ================= LSTM1: hidden cols [16*ng, 16*ng+16), K=1024 =================
    const int ng = bid;
    char* As = smem;                 // [64][128] bf16, rsB=256 (16KB)
    char* Ws = smem + 16384;         // [64][128] bf16 (16KB)
    auto Gx = (float (*)[64][16])(smem + 32768);  // [4][64][16] f32 (16KB)

    // prefetch epilogue operands (independent of the GEMM)
    float pg[4][4], pc[4];
#pragma unroll
    for (int q = 0; q < 4; ++q) {
      int b_ = ebrow + q * 16;
#pragma unroll
      for (int g = 0; g < 4; ++g)
        pg[q][g] = G1c[(size_t)(s * 64 + b_) * 4096 + g * 1024 + ng * 16 + ecol];
      pc[q] = c1[b_ * 1024 + ng * 16 + ecol];
    }

    bfx8 rA[4], rW[4];
    auto loadTile = [&](int it) {
#pragma unroll
      for (int i = 0; i < 4; ++i) {
        int r = tr + i * 16;
        rA[i] = *(const bfx8*)(h1_in + (size_t)r * 1024 + it * 128 + tc * 8);
        int wr = (r >> 4) * 1024 + ng * 16 + (r & 15);
        rW[i] = *(const bfx8*)(whh1b + (size_t)wr * 1024 + it * 128 + tc * 8);
      }
    };
    auto writeTile = [&]() {
#pragma unroll
      for (int i = 0; i < 4; ++i) {
        int r = tr + i * 16;
        int sw = (tc * 16) ^ ((r & 7) << 4);
        *(bfx8*)(As + r * 256 + sw) = rA[i];
        *(bfx8*)(Ws + r * 256 + sw) = rW[i];
      }
    };

    loadTile(0);
    fx4 acc[4] = {};
    for (int it = 0; it < 8; ++it) {
      writeTile();
      __syncthreads();
      if (it < 7) loadTile(it + 1);
#pragma unroll
      for (int ks = 0; ks < 4; ++ks) {
        const int cbB = ks * 64 + hi * 16;
        int rb = wv * 16 + rr;
        bfx8 bfr = *(const bfx8*)(Ws + rb * 256 + (cbB ^ ((rb & 7) << 4)));
#pragma unroll
        for (int m = 0; m < 4; ++m) {
          int ra = m * 16 + rr;
          bfx8 afr = *(const bfx8*)(As + ra * 256 + (cbB ^ ((ra & 7) << 4)));
          acc[m] = mfma16(afr, bfr, acc[m]);
        }
      }
      __syncthreads();
    }
    // wave wv holds gate wv: C row = batch (m*16+hi*4+r), col = gate-col (rr)
#pragma unroll
    for (int m = 0; m < 4; ++m)
#pragma unroll
      for (int r = 0; r < 4; ++r)
        Gx[wv][m * 16 + hi * 4 + r][rr] = acc[m][r];
    __syncthreads();
#pragma unroll
    for (int q = 0; q < 4; ++q) {
      int b_ = ebrow + q * 16;
      float gi = Gx[0][b_][ecol] + pg[q][0];
      float gf = Gx[1][b_][ecol] + pg[q][1];
      float gg = Gx[2][b_][ecol] + pg[q][2];
      float go = Gx[3][b_][ecol] + pg[q][3];
      float cn = fast_sig(gf) * pc[q] + fast_sig(gi) * fast_tanh(gg);
      int ci = b_ * 1024 + ng * 16 + ecol;
      c1[ci] = cn;
      h1_out[ci] = (__bf16)(fast_sig(go) * fast_tanh(cn));
    }
  } else {
    // ================= LSTM2: hidden cols [16*ng2, 16*ng2+16), K=256 =================
    if (!do_l2) return;
    const int ng2 = do_l1 ? bid - 64 : bid;
    char* Ws = smem;                 // [64][256] bf16, rsB=512 (32KB)
    char* As = smem + 32768;         // [64][256] bf16 (32KB)
    auto Gx = (float (*)[64][16])(smem + 65536);  // [4][64][16] f32 (16KB)

    float pg[4][4], pc[4];
#pragma unroll
    for (int q = 0; q < 4; ++q) {
      int b_ = ebrow + q * 16;
#pragma unroll
      for (int g = 0; g < 4; ++g)
        pg[q][g] = G2c[(size_t)(s * 64 + b_) * 1024 + g * 256 + ng2 * 16 + ecol];
      pc[q] = c2[b_ * 256 + ng2 * 16 + ecol];
    }

    for (int idx = tid; idx < 2048; idx += 256) {
      int r = idx >> 5, c = idx & 31;
      int wr = (r >> 4) * 256 + ng2 * 16 + (r & 15);
      *(bfx8*)(Ws + r * 512 + ((c * 16) ^ ((r & 7) << 4))) =
          *(const bfx8*)(whh2b + (size_t)wr * 256 + c * 8);
    }
    stage(As, 512, h2_in, 256, 2048, 5);
    __syncthreads();

    fx4 acc[4] = {};
#pragma unroll
    for (int ks = 0; ks < 8; ++ks) {
      const int cbB = ks * 64 + hi * 16;
      int rb = wv * 16 + rr;
      bfx8 bfr = *(const bfx8*)(Ws + rb * 512 + (cbB ^ ((rb & 7) << 4)));
#pragma unroll
      for (int m = 0; m < 4; ++m) {
        int ra = m * 16 + rr;
        bfx8 afr = *(const bfx8*)(As + ra * 512 + (cbB ^ ((ra & 7) << 4)));
        acc[m] = mfma16(afr, bfr, acc[m]);
      }
    }
    __syncthreads();
#pragma unroll
    for (int m = 0; m < 4; ++m)
#pragma unroll
      for (int r = 0; r < 4; ++r)
        Gx[wv][m * 16 + hi * 4 + r][rr] = acc[m][r];
    __syncthreads();
#pragma unroll
    for (int q = 0; q < 4; ++q) {
      int b_ = ebrow + q * 16;
      float gi = Gx[0][b_][ecol] + pg[q][0];
      float gf = Gx[1][b_][ecol] + pg[q][1];
      float gg = Gx[2][b_][ecol] + pg[q][2];
      float go = Gx[3][b_][ecol] + pg[q][3];
      float cn = fast_sig(gf) * pc[q] + fast_sig(gi) * fast_tanh(gg);
      int ci = b_ * 256 + ng2 * 16 + ecol;
      c2[ci] = cn;
      h2_out[ci] = (__bf16)(fast_sig(go) * fast_tanh(cn));
    }
  }
}

// ---- fc3 over all timesteps: out[32768 x 64] = H2mat[32768 x 256] @ w3[64 x 256]^T + b3
__launch_bounds__(256)
__global__ void k_fc3b(const __bf16* __restrict__ H2mat, const __bf16* __restrict__ w3,
                       const float* __restrict__ b3, float* __restrict__ out)
{
  __shared__ __align__(16) char smem[65536];
  const int tid = threadIdx.x, lane = tid & 63, wv = tid >> 6;
  const int rr = lane & 15, hi = lane >> 4;
  char* As = smem;             // [64][256] bf16
  char* Ws = smem + 32768;     // [64][256] bf16
  const size_t row0 = (size_t)blockIdx.x * 64;
  stage(As, 512, H2mat + row0 * 256, 256, 2048, 5);
  stage(Ws, 512, w3, 256, 2048, 5);
  __syncthreads();
  fx4 acc[4] = {};
#pragma unroll
  for (int ks = 0; ks < 8; ++ks) {
    const int cbB = ks * 64 + hi * 16;
    int rb = wv * 16 + rr;
    bfx8 bfr = *(const bfx8*)(Ws + rb * 512 + (cbB ^ ((rb & 7) << 4)));
#pragma unroll
    for (int m = 0; m < 4; ++m) {
      int ra = m * 16 + rr;
      bfx8 afr = *(const bfx8*)(As + ra * 512 + (cbB ^ ((ra & 7) << 4)));
      acc[m] = mfma16(afr, bfr, acc[m]);
    }
  }
  float bv = b3[wv * 16 + rr];
#pragma unroll
  for (int m = 0; m < 4; ++m)
#pragma unroll
    for (int r = 0; r < 4; ++r)
      out[(row0 + m * 16 + hi * 4 + r) * 64 + wv * 16 + rr] = acc[m][r] + bv;
}

// ---------------- host launcher ----------------
extern "C" void kernel_launch(void* const* d_in, const int* in_sizes, int n_in,
                              void* d_out, int out_size, void* d_ws, size_t ws_size,
                              hipStream_t stream)
{
  (void)in_sizes; (void)n_in; (void)out_size;
  const float* f_in = (const float*)d_in[0];
  const float* fc1w = (const float*)d_in[1];
  const float* fc1b = (const float*)d_in[2];
  const float* wih1 = (const float*)d_in[3];
  const float* whh1 = (const float*)d_in[4];
  const float* bih1 = (const float*)d_in[5];
  const float* bhh1 = (const float*)d_in[6];
  const float* fc2w = (const float*)d_in[7];
  const float* fc2b = (const float*)d_in[8];
  const float* wih2 = (const float*)d_in[9];
  const float* whh2 = (const float*)d_in[10];
  const float* bih2 = (const float*)d_in[11];
  const float* bhh2 = (const float*)d_in[12];
  const float* fc3w = (const float*)d_in[13];
  const float* fc3b = (const float*)d_in[14];
  float* out = (float*)d_out;

  char* base = (char*)d_ws;
  size_t off = 0;
  auto alloc = [&](size_t bytes) -> char* {
    char* q = base + off;
    off = (off + bytes + 255) & ~(size_t)255;
    return q;
  };
  // fixed region
  __bf16* wb_fc1 = (__bf16*)alloc((size_t)H_ * I_ * 2);
  __bf16* wb_ih1 = (__bf16*)alloc((size_t)G1N * H_ * 2);
  __bf16* wb_hh1 = (__bf16*)alloc((size_t)G1N * H1_ * 2);
  __bf16* wb_fc2 = (__bf16*)alloc((size_t)F2_ * H1_ * 2);
  __bf16* wb_ih2 = (__bf16*)alloc((size_t)G2N * F2_ * 2);
  __bf16* wb_hh2 = (__bf16*)alloc((size_t)G2N * H2_ * 2);
  __bf16* wb_fc3 = (__bf16*)alloc((size_t)O_ * H2_ * 2);
  __bf16* in_bf  = (__bf16*)alloc((size_t)T_ * B_ * I_ * 2);
  float*  bsum1  = (float*) alloc((size_t)G1N * 4);
  float*  bsum2  = (float*) alloc((size_t)G2N * 4);
  float*  c1     = (float*) alloc((size_t)B_ * H1_ * 4);
  float*  c2     = (float*) alloc((size_t)B_ * H2_ * 4);
  __bf16* h2a    = (__bf16*)alloc((size_t)(T_ + 1) * B_ * H2_ * 2);  // slots 0..512
  size_t fixed = off;

  // Tc-dependent region
  auto perTc = [](size_t Tc) -> size_t {
    size_t Mc = Tc * 64;
    return Mc * H_ * 2      // Xc
         + Mc * G1N * 4     // G1c
         + (Tc + 1) * (size_t)B_ * H1_ * 2   // h1c ring
         + Mc * F2_ * 2     // x2c
         + Mc * G2N * 4     // G2c
         + 6 * 256;         // alignment slop
  };
  int Tc = 128;
  while (Tc > 2 && fixed + perTc(Tc) > ws_size) Tc >>= 1;
  const int Mc = Tc * 64;
  __bf16* Xc  = (__bf16*)alloc((size_t)Mc * H_ * 2);
  float*  G1c = (float*) alloc((size_t)Mc * G1N * 4);
  __bf16* h1c = (__bf16*)alloc((size_t)(Tc + 1) * B_ * H1_ * 2);
  __bf16* x2c = (__bf16*)alloc((size_t)Mc * F2_ * 2);
  float*  G2c = (float*) alloc((size_t)Mc * G2N * 4);

  // conversions
  struct CV { const float* s; __bf16* d; int n; } cvs[8] = {
    {fc1w, wb_fc1, H_ * I_},   {wih1, wb_ih1, G1N * H_},  {whh1, wb_hh1, G1N * H1_},
    {fc2w, wb_fc2, F2_ * H1_}, {wih2, wb_ih2, G2N * F2_}, {whh2, wb_hh2, G2N * H2_},
    {fc3w, wb_fc3, O_ * H2_},  {f_in, in_bf, T_ * B_ * I_},
  };
  for (int i = 0; i < 8; ++i) {
    int n4 = cvs[i].n / 4;
    int blocks = (n4 + 255) / 256;
    if (blocks > 2048) blocks = 2048;
    k_f2b<<<blocks, 256, 0, stream>>>(cvs[i].s, cvs[i].d, n4);
  }
  k_add2<<<G1N / 256, 256, 0, stream>>>(bih1, bhh1, bsum1, G1N);
  k_add2<<<G2N / 256, 256, 0, stream>>>(bih2, bhh2, bsum2, G2N);
  // zero initial state
  hipMemsetAsync(c1, 0, (size_t)B_ * H1_ * 4, stream);
  hipMemsetAsync(c2, 0, (size_t)B_ * H2_ * 4, stream);
  hipMemsetAsync(h1c, 0, (size_t)B_ * H1_ * 2, stream);   // slot 0
  hipMemsetAsync(h2a, 0, (size_t)B_ * H2_ * 2, stream);   // slot 0

  const int chunks = T_ / Tc;
  const size_t H1SLOT = (size_t)B_ * H1_;   // 65536 elems
  const size_t H2SLOT = (size_t)B_ * H2_;   // 16384 elems
  for (int ch = 0; ch < chunks; ++ch) {
    // X1 = leaky(in @ fc1^T + b)
    k_gemm<<<dim3(H_ / 128, Mc / 128), 256, 0, stream>>>(
        in_bf + (size_t)ch * Mc * I_, wb_fc1, nullptr, Xc, fc1b, Mc, H_, I_, 1);
    // G1 = X1 @ wih1^T + bsum1 (fp32)
    k_gemm<<<dim3(G1N / 128, Mc / 128), 256, 0, stream>>>(
        Xc, wb_ih1, G1c, nullptr, bsum1, Mc, G1N, H_, 2);
    // scan: LSTM1(t) + LSTM2(t - Tc)
    for (int s = 0; s < Tc; ++s) {
      int t2 = (ch - 1) * Tc + s;
      const __bf16* h1i = h1c + (size_t)((s == 0 && ch > 0) ? Tc : s) * H1SLOT;
      __bf16* h1o = h1c + (size_t)(s + 1) * H1SLOT;
      const __bf16* h2i = h2a + (size_t)(t2 >= 0 ? t2 : 0) * H2SLOT;
      __bf16* h2o = h2a + (size_t)(t2 >= 0 ? t2 + 1 : 0) * H2SLOT;
      k_step<<<80, 256, 0, stream>>>(1, (int)(ch > 0), s,
                                     h1i, h1o, c1, wb_hh1, G1c,
                                     h2i, h2o, c2, wb_hh2, G2c);
    }
    // x2 = leaky(h1 @ wfc2^T + b);  G2 = x2 @ wih2^T + bsum2
    k_gemm<<<dim3(F2_ / 128, Mc / 128), 256, 0, stream>>>(
        h1c + H1SLOT, wb_fc2, nullptr, x2c, fc2b, Mc, F2_, H1_, 1);
    k_gemm<<<dim3(G2N / 128, Mc / 128), 256, 0, stream>>>(
        x2c, wb_ih2, G2c, nullptr, bsum2, Mc, G2N, F2_, 2);
  }
  // tail: LSTM2 for last chunk
  for (int s = 0; s < Tc; ++s) {
    int t2 = (chunks - 1) * Tc + s;
    k_step<<<16, 256, 0, stream>>>(0, 1, s,
                                   nullptr, nullptr, c1, wb_hh1, G1c,
                                   h2a + (size_t)t2 * H2SLOT, h2a + (size_t)(t2 + 1) * H2SLOT,
                                   c2, wb_hh2, G2c);
  }
  // fc3 over all t
  k_fc3b<<<(T_ * B_) / 64, 256, 0, stream>>>(h2a + H2SLOT, wb_fc3, fc3b, out);
}